// Round 17
// baseline (122.610 us; speedup 1.0000x reference)
//
#include <hip/hip_runtime.h>

#define B_  2
#define T_  2048
#define D_  1024
#define H_  16
#define DH_ 64
#define M_  4096   // B*T

typedef _Float16 f16;
typedef _Float16 f16x8 __attribute__((ext_vector_type(8)));
typedef _Float16 f16x4 __attribute__((ext_vector_type(4)));
typedef __fp16   fp16x2 __attribute__((ext_vector_type(2)));
typedef float    f32x4  __attribute__((ext_vector_type(4)));
typedef float    f32x16 __attribute__((ext_vector_type(16)));
typedef unsigned int u32;

__device__ __forceinline__ void async_ld16(const void* g, void* l) {
  __builtin_amdgcn_global_load_lds(
      (const __attribute__((address_space(1))) unsigned int*)g,
      (__attribute__((address_space(3))) unsigned int*)l,
      16, 0, 0);
}

__device__ __forceinline__ u32 pkrtz(float a, float b) {
  union { fp16x2 h; u32 u; } x;
  x.h = __builtin_amdgcn_cvt_pkrtz(a, b);
  return x.u;
}

// ---------------------------------------------------------------- convert ---
// blocks 0..8191: f32->f16 conversion.  blocks 8192..8193: per-batch padding
// length (dual-layout bool detector), written to lens_out[b].
__global__ __launch_bounds__(256) void convert_all(
    const float* __restrict__ q, const float* __restrict__ k, const float* __restrict__ v,
    const float* __restrict__ wq, const float* __restrict__ wk, const float* __restrict__ wv,
    const float* __restrict__ wo, const void* __restrict__ kpm_raw,
    f16* __restrict__ xh, f16* __restrict__ wh, int* __restrict__ lens_out) {
  int bid = blockIdx.x;
  if (bid >= 8192) {                // padding length for batch b
    int b = bid - 8192;
    __shared__ int s_c8, s_c32;
    if (threadIdx.x == 0) { s_c8 = 0; s_c32 = 0; }
    __syncthreads();
    int tid = threadIdx.x, lane = tid & 63;
    {
      const unsigned char* k8 = (const unsigned char*)kpm_raw + (long)b * T_;
      int cnt = 0;
      for (int j = tid; j < T_; j += 256) cnt += (k8[j] == 0) ? 1 : 0;
#pragma unroll
      for (int off = 1; off < 64; off <<= 1) cnt += __shfl_xor(cnt, off);
      if (lane == 0) atomicAdd(&s_c8, cnt);
    }
    {
      const int* k32 = (const int*)kpm_raw + (long)b * T_;
      int cnt = 0;
      for (int j = tid; j < T_; j += 256) cnt += (k32[j] == 0) ? 1 : 0;
#pragma unroll
      for (int off = 1; off < 64; off <<= 1) cnt += __shfl_xor(cnt, off);
      if (lane == 0) atomicAdd(&s_c32, cnt);
    }
    __syncthreads();
    if (tid == 0) lens_out[b] = (s_c8 == T_) ? s_c32 : s_c8;
    return;
  }
  const float* src;
  f16* dst;
  long base;
  if (bid < 6144) {                 // q,k,v : 3 x 4194304 elems, 2048 blocks each
    int r = bid >> 11;
    src = (r == 0) ? q : (r == 1) ? k : v;
    dst = xh + (long)r * 4194304;
    base = (long)(bid & 2047) * 2048;
  } else {                          // Wq,Wk,Wv,Wo : 4 x 1048576 elems, 512 blocks each
    int r = (bid - 6144) >> 9;
    src = (r == 0) ? wq : (r == 1) ? wk : (r == 2) ? wv : wo;
    dst = wh + (long)r * 1048576;
    base = (long)((bid - 6144) & 511) * 2048;
  }
  long e = base + (long)threadIdx.x * 8;
  const float4* s4 = (const float4*)(src + e);
  float4 f0 = s4[0], f1 = s4[1];
  f16x8 o;
  o[0] = (f16)f0.x; o[1] = (f16)f0.y; o[2] = (f16)f0.z; o[3] = (f16)f0.w;
  o[4] = (f16)f1.x; o[5] = (f16)f1.y; o[6] = (f16)f1.z; o[7] = (f16)f1.w;
  *(f16x8*)(dst + e) = o;
}

// ------------------------------------------------------------------- GEMM ---
// C = A(MxK) * W(NxK)^T.  M=4096, N=K=1024.  128x128 tile, BK=32, 8 waves
// (wave = 64x32 output).  3-slot LDS ring with depth-2 prefetch + counted
// vmcnt(2): tile t+2's loads ride across the barrier (T4), so stage latency
// gets ~2 iterations to hide.  2-way-optimal XOR chunk swizzle
// s(r)=((r&3)+((r>>2)&3))&3 (pre-swizzled global source, linear LDS dest,
// swizzled reader).  + XCD chunked swizzle.
// modes: 0 -> Qh (f16, *0.125*log2e)  1 -> Kh  2 -> Vt [b,h,dh,t]  3 -> f32
__global__ __launch_bounds__(512) void gemm_k(
    const f16* __restrict__ Abase, const f16* __restrict__ Wbase,
    f16* __restrict__ Qb, f16* __restrict__ Kb, f16* __restrict__ Vt,
    float* __restrict__ Co, int which) {
  __shared__ __align__(16) f16 As[3][4096];   // [slot][row*32 + phys_chunk*8]
  __shared__ __align__(16) f16 Bs[3][4096];
  const int K = 1024, N = 1024;

  // XCD-aware chunked swizzle (nwg = 768 or 256, both %8==0 -> bijective)
  int gx = gridDim.x, gy = gridDim.y;
  int nwg = gx * gy * gridDim.z;
  int bid = blockIdx.x + gx * (blockIdx.y + gy * blockIdx.z);
  int cpx = nwg >> 3;
  int wg = (bid & 7) * cpx + (bid >> 3);
  int bz = wg / (gx * gy);
  int rem = wg - bz * gx * gy;
  int by = rem / gx, bx = rem - by * gx;

  int mode;
  const f16 *A, *W;
  if (which) { mode = 3; A = Abase; W = Wbase; }
  else {
    mode = bz;
    A = Abase + (long)bz * 4194304;
    W = Wbase + (long)bz * 1048576;
  }
  int m0 = by * 128, n0 = bx * 128;
  int tid = threadIdx.x, lane = tid & 63, w = tid >> 6;
  int wr = w >> 2, wc = w & 3;     // wave tile: rows wr*64, cols wc*32

  // stage: thread covers row srow (0..127), physical 16B chunk sp (0..3);
  // global source column is the XOR-swizzled logical chunk.
  int srow = tid >> 2;
  int sp   = tid & 3;
  int ss   = ((srow & 3) + ((srow >> 2) & 3)) & 3;
  int scol = (sp ^ ss) * 8;        // f16 units
  const f16* pa = A + (long)(m0 + srow) * K + scol;
  const f16* pb = W + (long)(n0 + srow) * K + scol;
  int ldst = tid * 8;              // linear LDS dest (f16 units) = tid*16B

  f32x4 acc[4][2] = {};
  int row = lane & 15;
  int rs  = ((row & 3) + ((row >> 2) & 3)) & 3;
  int kq  = ((lane >> 4) ^ rs) * 8;   // swizzled read chunk (f16 units)

  auto STAGE = [&](int k0, int bsel) {
    async_ld16(pa + k0, &As[bsel][ldst]);
    async_ld16(pb + k0, &Bs[bsel][ldst]);
  };

  // prologue: tiles 0 and 1 staged; wait for tile 0 (tile 1's 2 loads ride)
  STAGE(0, 0);
  STAGE(32, 1);
  asm volatile("s_waitcnt vmcnt(2)" ::: "memory");
  __builtin_amdgcn_s_barrier();

  int it = 0;
  for (int k0 = 0; k0 < K; k0 += 32, ++it) {
    int c = it % 3;
    if (k0 + 64 < K) { int sn = (it + 2) % 3; STAGE(k0 + 64, sn); }
    f16x8 af[4], bfr[2];
#pragma unroll
    for (int m = 0; m < 4; m++)
      af[m] = *(const f16x8*)&As[c][(wr * 64 + m * 16 + row) * 32 + kq];
#pragma unroll
    for (int n = 0; n < 2; n++)
      bfr[n] = *(const f16x8*)&Bs[c][(wc * 32 + n * 16 + row) * 32 + kq];
#pragma unroll
    for (int m = 0; m < 4; m++)
#pragma unroll
      for (int n = 0; n < 2; n++)
        acc[m][n] = __builtin_amdgcn_mfma_f32_16x16x32_f16(af[m], bfr[n], acc[m][n], 0, 0, 0);
    // need tile it+1 resident after this barrier; tile it+2's 2 loads ride.
    if (k0 + 64 < K) asm volatile("s_waitcnt vmcnt(2)" ::: "memory");
    else             asm volatile("s_waitcnt vmcnt(0)" ::: "memory");
    __builtin_amdgcn_s_barrier();
  }

  int r0 = (lane >> 4) * 4;
#pragma unroll
  for (int m = 0; m < 4; m++) {
    int gmb = m0 + wr * 64 + m * 16 + r0;
#pragma unroll
    for (int n = 0; n < 2; n++) {
      int gn = n0 + wc * 32 + n * 16 + row;
      if (mode == 0) {
        // 0.125 (1/sqrt(DH)) * log2(e): attention works in exp2 domain
#pragma unroll
        for (int i = 0; i < 4; i++)
          Qb[(long)(gmb + i) * N + gn] = (f16)(acc[m][n][i] * 0.18033688f);
      } else if (mode == 1) {
#pragma unroll
        for (int i = 0; i < 4; i++)
          Kb[(long)(gmb + i) * N + gn] = (f16)acc[m][n][i];
      } else if (mode == 2) {
        int b = gmb >> 11;
        int t = gmb & 2047;
        int h = gn >> 6, dh = gn & 63;
        f16x4 pk;
#pragma unroll
        for (int i = 0; i < 4; i++) pk[i] = (f16)acc[m][n][i];
        *(f16x4*)&Vt[(long)((b * 16 + h) * 64 + dh) * 2048 + t] = pk;
      } else {
#pragma unroll
        for (int i = 0; i < 4; i++)
          Co[(long)(gmb + i) * N + gn] = acc[m][n][i];
      }
    }
  }
}

// -------------------------------------------------------------- attention ---
// LDS-staged flash attention, exp2-domain softmax, KVBLK=128 per round
// (two 64-key sub-tiles, joint online-softmax update), permlane32_swap for
// the P-fragment half-exchange. Block = 4 waves = 128 q-rows.
// (r14 best config: no setprio, no defer-max — both measured regressions.)
__global__ __launch_bounds__(256, 2) void attn_k(
    const f16* __restrict__ Q, const f16* __restrict__ Kp,
    const f16* __restrict__ Vt, const int* __restrict__ Lens,
    f16* __restrict__ Ao) {
  __shared__ __align__(16) f16 Kl[4][4096];   // 4 x 8KB K 64-tiles
  __shared__ __align__(16) f16 Vl[4][4096];   // 4 x 8KB V^T 64-tiles

  int tid = threadIdx.x, lane = tid & 63, w = tid >> 6;
  int bh = blockIdx.x;
  int j  = blockIdx.y;
  int qm = (j < 8) ? (15 - j) : (j - 8);   // anticorrelated length pairing
  int b = bh >> 4, h = bh & 15;
  int r31 = lane & 31, hi = lane >> 5, hi8 = hi * 8;

  int len = Lens[b];
  int q0 = qm * 128;
  int q0w = q0 + w * 32;
  int gq = q0w + r31;

  int blk_kmax = min(q0 + 128, len);       // block-level visible keys
  int wav_kmax = min(q0w + 32, len);       // this wave's visible keys
  int NR = (blk_kmax + 127) >> 7;          // block-uniform 128-wide rounds

  const f16* Qh = Q  + (long)b * T_ * D_ + h * 64;
  const f16* Kh = Kp + (long)b * T_ * D_ + h * 64;
  const f16* Vh = Vt + (long)(b * 16 + h) * 64 * T_;

  // stage-source constants: thread covers rows srow, srow+8 (shot s), chunk sc
  int srow = w * 16 + (lane >> 3);
  int sc8  = ((lane & 7) ^ ((lane >> 3) & 7)) * 8;   // swizzled 16B-chunk, f16 elems
  int ldst = w * 1024 + lane * 8;                    // f16 elems; +512 for shot 1

  // reader swizzled chunk offsets (constant per lane): logical chunk 2t+hi
  int coff[4];
#pragma unroll
  for (int t = 0; t < 4; t++) coff[t] = ((2 * t + hi) ^ (r31 & 7)) * 8;

  auto STAGE64 = [&](int t, int bsel) {    // tile t (64 keys) -> buffer bsel
    int kb = t * 64;                       // rows always < 2048: in-bounds
#pragma unroll
    for (int s = 0; s < 2; s++) {
      int row = srow + s * 8;
      async_ld16(Kh + (long)(kb + row) * D_ + sc8, &Kl[bsel][ldst + s * 512]);
      async_ld16(Vh + (long)row * T_ + kb + sc8,   &Vl[bsel][ldst + s * 512]);
    }
  };

  // Q fragments: lane holds Q[gq][16t + hi*8 .. +8]
  STAGE64(0, 0);
  STAGE64(1, 1);
  f16x8 qf[4];
#pragma unroll
  for (int t = 0; t < 4; t++)
    qf[t] = *(const f16x8*)(Qh + (long)gq * D_ + t * 16 + hi8);

  f32x16 o0 = {}, o1 = {};       // O^T partials: dh-tiles 0 (0..31), 1 (32..63)
  float mrun = -1e30f, lrun = 0.f;

  auto QK = [&](int buf, f32x16& sa, f32x16& sb) {
#pragma unroll
    for (int tq = 0; tq < 4; tq++) {
      f16x8 k0 = *(const f16x8*)&Kl[buf][(r31)      * 64 + coff[tq]];
      f16x8 k1 = *(const f16x8*)&Kl[buf][(32 + r31) * 64 + coff[tq]];
      sa = __builtin_amdgcn_mfma_f32_32x32x16_f16(k0, qf[tq], sa, 0, 0, 0);
      sb = __builtin_amdgcn_mfma_f32_32x32x16_f16(k1, qf[tq], sb, 0, 0, 0);
    }
  };

  auto MASK = [&](f32x16& sa, f32x16& sb, int kb) {
#pragma unroll
    for (int r = 0; r < 16; r++) {
      int pat = (r & 3) + 8 * (r >> 2) + 4 * hi;
      int gk0 = kb + pat, gk1 = kb + 32 + pat;
      if (gk0 > gq || gk0 >= len) sa[r] = -1e30f;
      if (gk1 > gq || gk1 >= len) sb[r] = -1e30f;
    }
  };

  // pack P (exp2'd scores) -> PV fragments via v_permlane32_swap_b32, 8 MFMA
  auto PV = [&](int bufV, f32x16& sa, f32x16& sb) {
    u32 a0 = pkrtz(sa[0],  sa[1]),  a1 = pkrtz(sa[2],  sa[3]);
    u32 b0 = pkrtz(sa[4],  sa[5]),  b1 = pkrtz(sa[6],  sa[7]);
    u32 c0 = pkrtz(sa[8],  sa[9]),  c1 = pkrtz(sa[10], sa[11]);
    u32 d0 = pkrtz(sa[12], sa[13]), d1 = pkrtz(sa[14], sa[15]);
    u32 e0 = pkrtz(sb[0],  sb[1]),  e1 = pkrtz(sb[2],  sb[3]);
    u32 f0_ = pkrtz(sb[4],  sb[5]), f1_ = pkrtz(sb[6],  sb[7]);
    u32 g0 = pkrtz(sb[8],  sb[9]),  g1 = pkrtz(sb[10], sb[11]);
    u32 h0 = pkrtz(sb[12], sb[13]), h1 = pkrtz(sb[14], sb[15]);
    // swap(X,Y): X <- {X.lo | Y.from-lo-for-hi}, Y <- {X.from-hi-for-lo | Y.hi}
    asm("v_permlane32_swap_b32 %0, %1" : "+v"(a0), "+v"(b0));
    asm("v_permlane32_swap_b32 %0, %1" : "+v"(a1), "+v"(b1));
    asm("v_permlane32_swap_b32 %0, %1" : "+v"(c0), "+v"(d0));
    asm("v_permlane32_swap_b32 %0, %1" : "+v"(c1), "+v"(d1));
    asm("v_permlane32_swap_b32 %0, %1" : "+v"(e0), "+v"(f0_));
    asm("v_permlane32_swap_b32 %0, %1" : "+v"(e1), "+v"(f1_));
    asm("v_permlane32_swap_b32 %0, %1" : "+v"(g0), "+v"(h0));
    asm("v_permlane32_swap_b32 %0, %1" : "+v"(g1), "+v"(h1));
    union { u32 w[4]; f16x8 v; } f00, f01, f10, f11;
    f00.w[0] = a0;  f00.w[1] = a1;  f00.w[2] = b0;  f00.w[3] = b1;
    f01.w[0] = c0;  f01.w[1] = c1;  f01.w[2] = d0;  f01.w[3] = d1;
    f10.w[0] = e0;  f10.w[1] = e1;  f10.w[2] = f0_; f10.w[3] = f1_;
    f11.w[0] = g0;  f11.w[1] = g1;  f11.w[2] = h0;  f11.w[3] = h1;

    f16x8 v00 = *(const f16x8*)&Vl[bufV][(r31)      * 64 + coff[0]];
    f16x8 v01 = *(const f16x8*)&Vl[bufV][(r31)      * 64 + coff[1]];
    f16x8 v02 = *(const f16x8*)&Vl[bufV][(r31)      * 64 + coff[2]];
    f16x8 v03 = *(const f16x8*)&Vl[bufV][(r31)      * 64 + coff[3]];
    f16x8 v10 = *(const f16x8*)&Vl[bufV][(32 + r31) * 64 + coff[0]];
    f16x8 v11 = *(const f16x8*)&Vl[bufV][(32 + r31) * 64 + coff[1]];
    f16x8 v12 = *(const f16x8*)&Vl[bufV][(32 + r31) * 64 + coff[2]];
    f16x8 v13 = *(const f16x8*)&Vl[bufV][(32 + r31) * 64 + coff[3]];

    o0 = __builtin_amdgcn_mfma_f32_32x32x16_f16(v00, f00.v, o0, 0, 0, 0);
    o0 = __builtin_amdgcn_mfma_f32_32x32x16_f16(v01, f01.v, o0, 0, 0, 0);
    o0 = __builtin_amdgcn_mfma_f32_32x32x16_f16(v02, f10.v, o0, 0, 0, 0);
    o0 = __builtin_amdgcn_mfma_f32_32x32x16_f16(v03, f11.v, o0, 0, 0, 0);
    o1 = __builtin_amdgcn_mfma_f32_32x32x16_f16(v10, f00.v, o1, 0, 0, 0);
    o1 = __builtin_amdgcn_mfma_f32_32x32x16_f16(v11, f01.v, o1, 0, 0, 0);
    o1 = __builtin_amdgcn_mfma_f32_32x32x16_f16(v12, f10.v, o1, 0, 0, 0);
    o1 = __builtin_amdgcn_mfma_f32_32x32x16_f16(v13, f11.v, o1, 0, 0, 0);
  };

  asm volatile("s_waitcnt vmcnt(0)" ::: "memory");
  __syncthreads();

  for (int r = 0; r < NR; r++) {
    int t0 = 2 * r;
    int b0buf = t0 & 3, b1buf = (t0 + 1) & 3;
    if (r + 1 < NR) { STAGE64(t0 + 2, (t0 + 2) & 3); STAGE64(t0 + 3, (t0 + 3) & 3); }

    int kb = r * 128;
    if (kb < wav_kmax) {
      bool has2 = (kb + 64) < wav_kmax;
      f32x16 s0 = {}, s1 = {}, s2, s3;
#pragma unroll
      for (int i = 0; i < 16; i++) { s2[i] = -1e30f; s3[i] = -1e30f; }

      QK(b0buf, s0, s1);
      if (has2) {
        f32x16 z0 = {}, z1 = {};
        QK(b1buf, z0, z1);
        s2 = z0; s3 = z1;
      }
      if (kb + 128 > q0w || kb + 128 > len) {
        MASK(s0, s1, kb);
        if (has2) MASK(s2, s3, kb + 64);
      }

      // joint max over (up to) 128 scores: tree + one half-exchange
      float t16[16];
#pragma unroll
      for (int rr = 0; rr < 16; rr++)
        t16[rr] = fmaxf(fmaxf(s0[rr], s1[rr]), fmaxf(s2[rr], s3[rr]));
#pragma unroll
      for (int s = 8; s > 0; s >>= 1)
#pragma unroll
        for (int rr = 0; rr < s; rr++) t16[rr] = fmaxf(t16[rr], t16[rr + s]);
      float mx = fmaxf(t16[0], __shfl_xor(t16[0], 32));

      float mnew = fmaxf(mrun, mx);
      float sf = exp2f(mrun - mnew);    // exp2 domain (log2e folded into Q)
      mrun = mnew;

      float ps[4] = {0.f, 0.f, 0.f, 0.f};
#pragma unroll
      for (int rr = 0; rr < 16; rr++) {
        s0[rr] = exp2f(s0[rr] - mnew);  ps[rr & 3] += s0[rr];
        s1[rr] = exp2f(s1[rr] - mnew);  ps[rr & 3] += s1[rr];
      }
      if (has2) {
#pragma unroll
        for (int rr = 0; rr < 16; rr++) {
          s2[rr] = exp2f(s2[rr] - mnew);  ps[rr & 3] += s2[rr];
          s3[rr] = exp2f(s3[rr] - mnew);  ps[rr & 3] += s3[rr];
        }
      }
      float psum = (ps[0] + ps[1]) + (ps[2] + ps[3]);
      lrun = lrun * sf + psum + __shfl_xor(psum, 32);

      o0 *= sf;
      o1 *= sf;

      PV(b0buf, s0, s1);
      if (has2) PV(b1buf, s2, s3);
    }

    asm volatile("s_waitcnt vmcnt(0)" ::: "memory");
    __syncthreads();
  }

  float linv = 1.f / lrun;
  f16* Aob = Ao + (long)(b * T_ + gq) * D_ + h * 64 + 4 * hi;
#pragma unroll
  for (int g = 0; g < 4; g++) {
    f16x4 s0, s1;
#pragma unroll
    for (int i = 0; i < 4; i++) {
      s0[i] = (f16)(o0[g * 4 + i] * linv);
      s1[i] = (f16)(o1[g * 4 + i] * linv);
    }
    *(f16x4*)(Aob + 8 * g)      = s0;
    *(f16x4*)(Aob + 32 + 8 * g) = s1;
  }
}

// ------------------------------------------------------------------ launch ---
extern "C" void kernel_launch(void* const* d_in, const int* in_sizes, int n_in,
                              void* d_out, int out_size, void* d_ws, size_t ws_size,
                              hipStream_t stream) {
  const float* q  = (const float*)d_in[0];
  const float* k  = (const float*)d_in[1];
  const float* v  = (const float*)d_in[2];
  // d_in[3] = causal mask (analytic, unused)
  const void* kpm = d_in[4];
  const float* wq = (const float*)d_in[5];
  const float* wk = (const float*)d_in[6];
  const float* wv = (const float*)d_in[7];
  const float* wo = (const float*)d_in[8];

  char* ws = (char*)d_ws;
  f16* Xh = (f16*)(ws);                     // 3 * 8 MB
  f16* Wh = (f16*)(ws + 25165824);          // 4 * 2 MB
  f16* Qb = (f16*)(ws + 33554432);          // 8 MB
  f16* Kb = (f16*)(ws + 41943040);          // 8 MB
  f16* Vt = (f16*)(ws + 50331648);          // 8 MB
  f16* Ao = (f16*)(ws + 58720256);          // 8 MB  (total 64 MB)
  // Lens scratch: first 2 ints of d_out — read by attn, then fully
  // overwritten by the final GEMM.
  int* Lens = (int*)d_out;

  convert_all<<<8194, 256, 0, stream>>>(q, k, v, wq, wk, wv, wo, kpm, Xh, Wh, Lens);

  gemm_k<<<dim3(8, 32, 3), 512, 0, stream>>>(Xh, Wh, Qb, Kb, Vt, nullptr, 0);

  attn_k<<<dim3(B_ * H_, T_ / 128), 256, 0, stream>>>(Qb, Kb, Vt, Lens, Ao);

  gemm_k<<<dim3(8, 32, 1), 512, 0, stream>>>(Ao, Wh + 3 * 1048576, nullptr, nullptr,
                                             nullptr, (float*)d_out, 1);
}

// Round 18
// 115.287 us; speedup vs baseline: 1.0635x; 1.0635x over previous
//
#include <hip/hip_runtime.h>

#define B_  2
#define T_  2048
#define D_  1024
#define H_  16
#define DH_ 64
#define M_  4096   // B*T

typedef _Float16 f16;
typedef _Float16 f16x8 __attribute__((ext_vector_type(8)));
typedef _Float16 f16x4 __attribute__((ext_vector_type(4)));
typedef __fp16   fp16x2 __attribute__((ext_vector_type(2)));
typedef float    f32x4  __attribute__((ext_vector_type(4)));
typedef float    f32x16 __attribute__((ext_vector_type(16)));
typedef unsigned int u32;

__device__ __forceinline__ void async_ld16(const void* g, void* l) {
  __builtin_amdgcn_global_load_lds(
      (const __attribute__((address_space(1))) unsigned int*)g,
      (__attribute__((address_space(3))) unsigned int*)l,
      16, 0, 0);
}

__device__ __forceinline__ u32 pkrtz(float a, float b) {
  union { fp16x2 h; u32 u; } x;
  x.h = __builtin_amdgcn_cvt_pkrtz(a, b);
  return x.u;
}

// ---------------------------------------------------------------- convert ---
// blocks 0..2047: Wq/Wk/Wv/Wo f32->f16 (512 blocks each).
// blocks 2048..2049: per-batch padding length (dual-layout bool detector).
// X (q/k/v) is no longer converted here — the proj GEMM reads f32 directly.
__global__ __launch_bounds__(256) void convert_w(
    const float* __restrict__ wq, const float* __restrict__ wk, const float* __restrict__ wv,
    const float* __restrict__ wo, const void* __restrict__ kpm_raw,
    f16* __restrict__ wh, int* __restrict__ lens_out) {
  int bid = blockIdx.x;
  if (bid >= 2048) {                // padding length for batch b
    int b = bid - 2048;
    __shared__ int s_c8, s_c32;
    if (threadIdx.x == 0) { s_c8 = 0; s_c32 = 0; }
    __syncthreads();
    int tid = threadIdx.x, lane = tid & 63;
    {
      const unsigned char* k8 = (const unsigned char*)kpm_raw + (long)b * T_;
      int cnt = 0;
      for (int j = tid; j < T_; j += 256) cnt += (k8[j] == 0) ? 1 : 0;
#pragma unroll
      for (int off = 1; off < 64; off <<= 1) cnt += __shfl_xor(cnt, off);
      if (lane == 0) atomicAdd(&s_c8, cnt);
    }
    {
      const int* k32 = (const int*)kpm_raw + (long)b * T_;
      int cnt = 0;
      for (int j = tid; j < T_; j += 256) cnt += (k32[j] == 0) ? 1 : 0;
#pragma unroll
      for (int off = 1; off < 64; off <<= 1) cnt += __shfl_xor(cnt, off);
      if (lane == 0) atomicAdd(&s_c32, cnt);
    }
    __syncthreads();
    if (tid == 0) lens_out[b] = (s_c8 == T_) ? s_c32 : s_c8;
    return;
  }
  int r = bid >> 9;
  const float* src = (r == 0) ? wq : (r == 1) ? wk : (r == 2) ? wv : wo;
  f16* dst = wh + (long)r * 1048576;
  long base = (long)(bid & 511) * 2048;
  long e = base + (long)threadIdx.x * 8;
  const float4* s4 = (const float4*)(src + e);
  float4 f0 = s4[0], f1 = s4[1];
  f16x8 o;
  o[0] = (f16)f0.x; o[1] = (f16)f0.y; o[2] = (f16)f0.z; o[3] = (f16)f0.w;
  o[4] = (f16)f1.x; o[5] = (f16)f1.y; o[6] = (f16)f1.z; o[7] = (f16)f1.w;
  *(f16x8*)(dst + e) = o;
}

// ------------------------------------------------------------------- GEMM ---
// C = A(MxK) * W(NxK)^T.  M=4096, N=K=1024.  128x128 tile, BK=32, 8 waves
// (wave = 64x32 output), 2-slot double-buffered LDS (r14 structure).
// AF32=true (proj): A read directly as f32 from q/k/v, converted in-register
//   (RNE casts) and ds_write'd to LDS — kills the separate X convert pass.
// AF32=false (out): A is f16 (Ao), staged via global_load_lds.
// B always f16 via global_load_lds.  2-way-optimal XOR chunk swizzle
// s(r)=((r&3)+((r>>2)&3))&3 on source + reader.  + XCD chunked swizzle.
// modes: 0 -> Qh (f16, *0.125*log2e)  1 -> Kh  2 -> Vt [b,h,dh,t]  3 -> f32
template <bool AF32>
__global__ __launch_bounds__(512) void gemm_k(
    const float* __restrict__ Aq, const float* __restrict__ Ak,
    const float* __restrict__ Av, const f16* __restrict__ A16,
    const f16* __restrict__ Wbase,
    f16* __restrict__ Qb, f16* __restrict__ Kb, f16* __restrict__ Vt,
    float* __restrict__ Co) {
  __shared__ __align__(16) f16 As[2][4096];   // [buf][row*32 + phys_chunk*8]
  __shared__ __align__(16) f16 Bs[2][4096];
  const int K = 1024, N = 1024;

  // XCD-aware chunked swizzle (nwg = 768 or 256, both %8==0 -> bijective)
  int gx = gridDim.x, gy = gridDim.y;
  int nwg = gx * gy * gridDim.z;
  int bid = blockIdx.x + gx * (blockIdx.y + gy * blockIdx.z);
  int cpx = nwg >> 3;
  int wg = (bid & 7) * cpx + (bid >> 3);
  int bz = wg / (gx * gy);
  int rem = wg - bz * gx * gy;
  int by = rem / gx, bx = rem - by * gx;

  int mode = AF32 ? bz : 3;
  const float* A32 = nullptr;
  const f16*   Af  = nullptr;
  if (AF32) A32 = (bz == 0) ? Aq : (bz == 1) ? Ak : Av;
  else      Af  = A16;
  const f16* W = AF32 ? (Wbase + (long)bz * 1048576) : Wbase;

  int m0 = by * 128, n0 = bx * 128;
  int tid = threadIdx.x, lane = tid & 63, w = tid >> 6;
  int wr = w >> 2, wc = w & 3;     // wave tile: rows wr*64, cols wc*32

  // stage: thread covers row srow (0..127), physical 16B chunk sp (0..3);
  // global source column is the XOR-swizzled logical chunk.
  int srow = tid >> 2;
  int sp   = tid & 3;
  int ss   = ((srow & 3) + ((srow >> 2) & 3)) & 3;
  int scol = (sp ^ ss) * 8;        // element units (f16 or f32)
  const float* pa32 = AF32 ? (A32 + (long)(m0 + srow) * K + scol) : nullptr;
  const f16*   pa16 = AF32 ? nullptr : (Af + (long)(m0 + srow) * K + scol);
  const f16*   pb   = W + (long)(n0 + srow) * K + scol;
  int ldst = tid * 8;              // linear LDS dest (f16 units) = tid*16B

  f32x4 acc[4][2] = {};
  int row = lane & 15;
  int rs  = ((row & 3) + ((row >> 2) & 3)) & 3;
  int kq  = ((lane >> 4) ^ rs) * 8;   // swizzled read chunk (f16 units)

  float4 fa0, fa1;                 // in-flight f32 A chunk (AF32 path)
  auto LOADA32 = [&](int k0) {
    const float4* p = (const float4*)(pa32 + k0);
    fa0 = p[0]; fa1 = p[1];
  };
  auto WRITEA = [&](int bsel) {    // RNE casts, 16B ds_write
    f16x8 h;
    h[0] = (f16)fa0.x; h[1] = (f16)fa0.y; h[2] = (f16)fa0.z; h[3] = (f16)fa0.w;
    h[4] = (f16)fa1.x; h[5] = (f16)fa1.y; h[6] = (f16)fa1.z; h[7] = (f16)fa1.w;
    *(f16x8*)&As[bsel][ldst] = h;
  };

  // prologue: tile 0
  if (AF32) {
    LOADA32(0);
    WRITEA(0);                             // compiler waits the f32 loads
    async_ld16(pb, &Bs[0][ldst]);
  } else {
    async_ld16(pa16, &As[0][ldst]);
    async_ld16(pb,   &Bs[0][ldst]);
  }
  asm volatile("s_waitcnt vmcnt(0) lgkmcnt(0)" ::: "memory");
  __builtin_amdgcn_s_barrier();

  int cur = 0;
  for (int k0 = 0; k0 < K; k0 += 32) {
    bool more = (k0 + 32 < K);
    if (more) {
      if (AF32) {
        LOADA32(k0 + 32);                  // issue f32 loads early (ride over compute)
        async_ld16(pb + k0 + 32, &Bs[cur ^ 1][ldst]);
      } else {
        async_ld16(pa16 + k0 + 32, &As[cur ^ 1][ldst]);
        async_ld16(pb   + k0 + 32, &Bs[cur ^ 1][ldst]);
      }
    }
    f16x8 af[4], bfr[2];
#pragma unroll
    for (int m = 0; m < 4; m++)
      af[m] = *(const f16x8*)&As[cur][(wr * 64 + m * 16 + row) * 32 + kq];
#pragma unroll
    for (int n = 0; n < 2; n++)
      bfr[n] = *(const f16x8*)&Bs[cur][(wc * 32 + n * 16 + row) * 32 + kq];
#pragma unroll
    for (int m = 0; m < 4; m++)
#pragma unroll
      for (int n = 0; n < 2; n++)
        acc[m][n] = __builtin_amdgcn_mfma_f32_16x16x32_f16(af[m], bfr[n], acc[m][n], 0, 0, 0);
    if (AF32 && more) WRITEA(cur ^ 1);     // convert + LDS write (late)
    asm volatile("s_waitcnt vmcnt(0) lgkmcnt(0)" ::: "memory");
    __builtin_amdgcn_s_barrier();
    cur ^= 1;
  }

  int r0 = (lane >> 4) * 4;
#pragma unroll
  for (int m = 0; m < 4; m++) {
    int gmb = m0 + wr * 64 + m * 16 + r0;
#pragma unroll
    for (int n = 0; n < 2; n++) {
      int gn = n0 + wc * 32 + n * 16 + row;
      if (mode == 0) {
        // 0.125 (1/sqrt(DH)) * log2(e): attention works in exp2 domain
#pragma unroll
        for (int i = 0; i < 4; i++)
          Qb[(long)(gmb + i) * N + gn] = (f16)(acc[m][n][i] * 0.18033688f);
      } else if (mode == 1) {
#pragma unroll
        for (int i = 0; i < 4; i++)
          Kb[(long)(gmb + i) * N + gn] = (f16)acc[m][n][i];
      } else if (mode == 2) {
        int b = gmb >> 11;
        int t = gmb & 2047;
        int h = gn >> 6, dh = gn & 63;
        f16x4 pk;
#pragma unroll
        for (int i = 0; i < 4; i++) pk[i] = (f16)acc[m][n][i];
        *(f16x4*)&Vt[(long)((b * 16 + h) * 64 + dh) * 2048 + t] = pk;
      } else {
#pragma unroll
        for (int i = 0; i < 4; i++)
          Co[(long)(gmb + i) * N + gn] = acc[m][n][i];
      }
    }
  }
}

// -------------------------------------------------------------- attention ---
// LDS-staged flash attention, exp2-domain softmax, KVBLK=128 per round
// (two 64-key sub-tiles, joint online-softmax update), permlane32_swap for
// the P-fragment half-exchange. Block = 4 waves = 128 q-rows.
// (r14 best config: no setprio, no defer-max — both measured regressions.)
__global__ __launch_bounds__(256, 2) void attn_k(
    const f16* __restrict__ Q, const f16* __restrict__ Kp,
    const f16* __restrict__ Vt, const int* __restrict__ Lens,
    f16* __restrict__ Ao) {
  __shared__ __align__(16) f16 Kl[4][4096];   // 4 x 8KB K 64-tiles
  __shared__ __align__(16) f16 Vl[4][4096];   // 4 x 8KB V^T 64-tiles

  int tid = threadIdx.x, lane = tid & 63, w = tid >> 6;
  int bh = blockIdx.x;
  int j  = blockIdx.y;
  int qm = (j < 8) ? (15 - j) : (j - 8);   // anticorrelated length pairing
  int b = bh >> 4, h = bh & 15;
  int r31 = lane & 31, hi = lane >> 5, hi8 = hi * 8;

  int len = Lens[b];
  int q0 = qm * 128;
  int q0w = q0 + w * 32;
  int gq = q0w + r31;

  int blk_kmax = min(q0 + 128, len);       // block-level visible keys
  int wav_kmax = min(q0w + 32, len);       // this wave's visible keys
  int NR = (blk_kmax + 127) >> 7;          // block-uniform 128-wide rounds

  const f16* Qh = Q  + (long)b * T_ * D_ + h * 64;
  const f16* Kh = Kp + (long)b * T_ * D_ + h * 64;
  const f16* Vh = Vt + (long)(b * 16 + h) * 64 * T_;

  // stage-source constants: thread covers rows srow, srow+8 (shot s), chunk sc
  int srow = w * 16 + (lane >> 3);
  int sc8  = ((lane & 7) ^ ((lane >> 3) & 7)) * 8;   // swizzled 16B-chunk, f16 elems
  int ldst = w * 1024 + lane * 8;                    // f16 elems; +512 for shot 1

  // reader swizzled chunk offsets (constant per lane): logical chunk 2t+hi
  int coff[4];
#pragma unroll
  for (int t = 0; t < 4; t++) coff[t] = ((2 * t + hi) ^ (r31 & 7)) * 8;

  auto STAGE64 = [&](int t, int bsel) {    // tile t (64 keys) -> buffer bsel
    int kb = t * 64;                       // rows always < 2048: in-bounds
#pragma unroll
    for (int s = 0; s < 2; s++) {
      int row = srow + s * 8;
      async_ld16(Kh + (long)(kb + row) * D_ + sc8, &Kl[bsel][ldst + s * 512]);
      async_ld16(Vh + (long)row * T_ + kb + sc8,   &Vl[bsel][ldst + s * 512]);
    }
  };

  // Q fragments: lane holds Q[gq][16t + hi*8 .. +8]
  STAGE64(0, 0);
  STAGE64(1, 1);
  f16x8 qf[4];
#pragma unroll
  for (int t = 0; t < 4; t++)
    qf[t] = *(const f16x8*)(Qh + (long)gq * D_ + t * 16 + hi8);

  f32x16 o0 = {}, o1 = {};       // O^T partials: dh-tiles 0 (0..31), 1 (32..63)
  float mrun = -1e30f, lrun = 0.f;

  auto QK = [&](int buf, f32x16& sa, f32x16& sb) {
#pragma unroll
    for (int tq = 0; tq < 4; tq++) {
      f16x8 k0 = *(const f16x8*)&Kl[buf][(r31)      * 64 + coff[tq]];
      f16x8 k1 = *(const f16x8*)&Kl[buf][(32 + r31) * 64 + coff[tq]];
      sa = __builtin_amdgcn_mfma_f32_32x32x16_f16(k0, qf[tq], sa, 0, 0, 0);
      sb = __builtin_amdgcn_mfma_f32_32x32x16_f16(k1, qf[tq], sb, 0, 0, 0);
    }
  };

  auto MASK = [&](f32x16& sa, f32x16& sb, int kb) {
#pragma unroll
    for (int r = 0; r < 16; r++) {
      int pat = (r & 3) + 8 * (r >> 2) + 4 * hi;
      int gk0 = kb + pat, gk1 = kb + 32 + pat;
      if (gk0 > gq || gk0 >= len) sa[r] = -1e30f;
      if (gk1 > gq || gk1 >= len) sb[r] = -1e30f;
    }
  };

  // pack P (exp2'd scores) -> PV fragments via v_permlane32_swap_b32, 8 MFMA
  auto PV = [&](int bufV, f32x16& sa, f32x16& sb) {
    u32 a0 = pkrtz(sa[0],  sa[1]),  a1 = pkrtz(sa[2],  sa[3]);
    u32 b0 = pkrtz(sa[4],  sa[5]),  b1 = pkrtz(sa[6],  sa[7]);
    u32 c0 = pkrtz(sa[8],  sa[9]),  c1 = pkrtz(sa[10], sa[11]);
    u32 d0 = pkrtz(sa[12], sa[13]), d1 = pkrtz(sa[14], sa[15]);
    u32 e0 = pkrtz(sb[0],  sb[1]),  e1 = pkrtz(sb[2],  sb[3]);
    u32 f0_ = pkrtz(sb[4],  sb[5]), f1_ = pkrtz(sb[6],  sb[7]);
    u32 g0 = pkrtz(sb[8],  sb[9]),  g1 = pkrtz(sb[10], sb[11]);
    u32 h0 = pkrtz(sb[12], sb[13]), h1 = pkrtz(sb[14], sb[15]);
    // swap(X,Y): X <- {X.lo | Y.from-lo-for-hi}, Y <- {X.from-hi-for-lo | Y.hi}
    asm("v_permlane32_swap_b32 %0, %1" : "+v"(a0), "+v"(b0));
    asm("v_permlane32_swap_b32 %0, %1" : "+v"(a1), "+v"(b1));
    asm("v_permlane32_swap_b32 %0, %1" : "+v"(c0), "+v"(d0));
    asm("v_permlane32_swap_b32 %0, %1" : "+v"(c1), "+v"(d1));
    asm("v_permlane32_swap_b32 %0, %1" : "+v"(e0), "+v"(f0_));
    asm("v_permlane32_swap_b32 %0, %1" : "+v"(e1), "+v"(f1_));
    asm("v_permlane32_swap_b32 %0, %1" : "+v"(g0), "+v"(h0));
    asm("v_permlane32_swap_b32 %0, %1" : "+v"(g1), "+v"(h1));
    union { u32 w[4]; f16x8 v; } f00, f01, f10, f11;
    f00.w[0] = a0;  f00.w[1] = a1;  f00.w[2] = b0;  f00.w[3] = b1;
    f01.w[0] = c0;  f01.w[1] = c1;  f01.w[2] = d0;  f01.w[3] = d1;
    f10.w[0] = e0;  f10.w[1] = e1;  f10.w[2] = f0_; f10.w[3] = f1_;
    f11.w[0] = g0;  f11.w[1] = g1;  f11.w[2] = h0;  f11.w[3] = h1;

    f16x8 v00 = *(const f16x8*)&Vl[bufV][(r31)      * 64 + coff[0]];
    f16x8 v01 = *(const f16x8*)&Vl[bufV][(r31)      * 64 + coff[1]];
    f16x8 v02 = *(const f16x8*)&Vl[bufV][(r31)      * 64 + coff[2]];
    f16x8 v03 = *(const f16x8*)&Vl[bufV][(r31)      * 64 + coff[3]];
    f16x8 v10 = *(const f16x8*)&Vl[bufV][(32 + r31) * 64 + coff[0]];
    f16x8 v11 = *(const f16x8*)&Vl[bufV][(32 + r31) * 64 + coff[1]];
    f16x8 v12 = *(const f16x8*)&Vl[bufV][(32 + r31) * 64 + coff[2]];
    f16x8 v13 = *(const f16x8*)&Vl[bufV][(32 + r31) * 64 + coff[3]];

    o0 = __builtin_amdgcn_mfma_f32_32x32x16_f16(v00, f00.v, o0, 0, 0, 0);
    o0 = __builtin_amdgcn_mfma_f32_32x32x16_f16(v01, f01.v, o0, 0, 0, 0);
    o0 = __builtin_amdgcn_mfma_f32_32x32x16_f16(v02, f10.v, o0, 0, 0, 0);
    o0 = __builtin_amdgcn_mfma_f32_32x32x16_f16(v03, f11.v, o0, 0, 0, 0);
    o1 = __builtin_amdgcn_mfma_f32_32x32x16_f16(v10, f00.v, o1, 0, 0, 0);
    o1 = __builtin_amdgcn_mfma_f32_32x32x16_f16(v11, f01.v, o1, 0, 0, 0);
    o1 = __builtin_amdgcn_mfma_f32_32x32x16_f16(v12, f10.v, o1, 0, 0, 0);
    o1 = __builtin_amdgcn_mfma_f32_32x32x16_f16(v13, f11.v, o1, 0, 0, 0);
  };

  asm volatile("s_waitcnt vmcnt(0)" ::: "memory");
  __syncthreads();

  for (int r = 0; r < NR; r++) {
    int t0 = 2 * r;
    int b0buf = t0 & 3, b1buf = (t0 + 1) & 3;
    if (r + 1 < NR) { STAGE64(t0 + 2, (t0 + 2) & 3); STAGE64(t0 + 3, (t0 + 3) & 3); }

    int kb = r * 128;
    if (kb < wav_kmax) {
      bool has2 = (kb + 64) < wav_kmax;
      f32x16 s0 = {}, s1 = {}, s2, s3;
#pragma unroll
      for (int i = 0; i < 16; i++) { s2[i] = -1e30f; s3[i] = -1e30f; }

      QK(b0buf, s0, s1);
      if (has2) {
        f32x16 z0 = {}, z1 = {};
        QK(b1buf, z0, z1);
        s2 = z0; s3 = z1;
      }
      if (kb + 128 > q0w || kb + 128 > len) {
        MASK(s0, s1, kb);
        if (has2) MASK(s2, s3, kb + 64);
      }

      // joint max over (up to) 128 scores: tree + one half-exchange
      float t16[16];
#pragma unroll
      for (int rr = 0; rr < 16; rr++)
        t16[rr] = fmaxf(fmaxf(s0[rr], s1[rr]), fmaxf(s2[rr], s3[rr]));
#pragma unroll
      for (int s = 8; s > 0; s >>= 1)
#pragma unroll
        for (int rr = 0; rr < s; rr++) t16[rr] = fmaxf(t16[rr], t16[rr + s]);
      float mx = fmaxf(t16[0], __shfl_xor(t16[0], 32));

      float mnew = fmaxf(mrun, mx);
      float sf = exp2f(mrun - mnew);    // exp2 domain (log2e folded into Q)
      mrun = mnew;

      float ps[4] = {0.f, 0.f, 0.f, 0.f};
#pragma unroll
      for (int rr = 0; rr < 16; rr++) {
        s0[rr] = exp2f(s0[rr] - mnew);  ps[rr & 3] += s0[rr];
        s1[rr] = exp2f(s1[rr] - mnew);  ps[rr & 3] += s1[rr];
      }
      if (has2) {
#pragma unroll
        for (int rr = 0; rr < 16; rr++) {
          s2[rr] = exp2f(s2[rr] - mnew);  ps[rr & 3] += s2[rr];
          s3[rr] = exp2f(s3[rr] - mnew);  ps[rr & 3] += s3[rr];
        }
      }
      float psum = (ps[0] + ps[1]) + (ps[2] + ps[3]);
      lrun = lrun * sf + psum + __shfl_xor(psum, 32);

      o0 *= sf;
      o1 *= sf;

      PV(b0buf, s0, s1);
      if (has2) PV(b1buf, s2, s3);
    }

    asm volatile("s_waitcnt vmcnt(0)" ::: "memory");
    __syncthreads();
  }

  float linv = 1.f / lrun;
  f16* Aob = Ao + (long)(b * T_ + gq) * D_ + h * 64 + 4 * hi;
#pragma unroll
  for (int g = 0; g < 4; g++) {
    f16x4 s0, s1;
#pragma unroll
    for (int i = 0; i < 4; i++) {
      s0[i] = (f16)(o0[g * 4 + i] * linv);
      s1[i] = (f16)(o1[g * 4 + i] * linv);
    }
    *(f16x4*)(Aob + 8 * g)      = s0;
    *(f16x4*)(Aob + 32 + 8 * g) = s1;
  }
}

// ------------------------------------------------------------------ launch ---
extern "C" void kernel_launch(void* const* d_in, const int* in_sizes, int n_in,
                              void* d_out, int out_size, void* d_ws, size_t ws_size,
                              hipStream_t stream) {
  const float* q  = (const float*)d_in[0];
  const float* k  = (const float*)d_in[1];
  const float* v  = (const float*)d_in[2];
  // d_in[3] = causal mask (analytic, unused)
  const void* kpm = d_in[4];
  const float* wq = (const float*)d_in[5];
  const float* wk = (const float*)d_in[6];
  const float* wv = (const float*)d_in[7];
  const float* wo = (const float*)d_in[8];

  char* ws = (char*)d_ws;
  f16* Wh = (f16*)(ws);                     // 4 * 2 MB
  f16* Qb = (f16*)(ws + 8388608);           // 8 MB
  f16* Kb = (f16*)(ws + 16777216);          // 8 MB
  f16* Vt = (f16*)(ws + 25165824);          // 8 MB
  f16* Ao = (f16*)(ws + 33554432);          // 8 MB  (total 40 MB)
  // Lens scratch: first 2 ints of d_out — read by attn, then fully
  // overwritten by the final GEMM.
  int* Lens = (int*)d_out;

  convert_w<<<2050, 256, 0, stream>>>(wq, wk, wv, wo, kpm, Wh, Lens);

  gemm_k<true><<<dim3(8, 32, 3), 512, 0, stream>>>(
      q, k, v, nullptr, Wh, Qb, Kb, Vt, nullptr);

  attn_k<<<dim3(B_ * H_, T_ / 128), 256, 0, stream>>>(Qb, Kb, Vt, Lens, Ao);

  gemm_k<false><<<dim3(8, 32, 1), 512, 0, stream>>>(
      nullptr, nullptr, nullptr, Ao, Wh + 3 * 1048576, nullptr, nullptr, nullptr,
      (float*)d_out);
}

// Round 19
// 114.156 us; speedup vs baseline: 1.0741x; 1.0099x over previous
//
#include <hip/hip_runtime.h>

#define B_  2
#define T_  2048
#define D_  1024
#define H_  16
#define DH_ 64
#define M_  4096   // B*T

typedef _Float16 f16;
typedef _Float16 f16x8 __attribute__((ext_vector_type(8)));
typedef _Float16 f16x4 __attribute__((ext_vector_type(4)));
typedef __fp16   fp16x2 __attribute__((ext_vector_type(2)));
typedef float    f32x4  __attribute__((ext_vector_type(4)));
typedef float    f32x16 __attribute__((ext_vector_type(16)));
typedef unsigned int u32;

__device__ __forceinline__ void async_ld16(const void* g, void* l) {
  __builtin_amdgcn_global_load_lds(
      (const __attribute__((address_space(1))) unsigned int*)g,
      (__attribute__((address_space(3))) unsigned int*)l,
      16, 0, 0);
}

__device__ __forceinline__ u32 pkrtz(float a, float b) {
  union { fp16x2 h; u32 u; } x;
  x.h = __builtin_amdgcn_cvt_pkrtz(a, b);
  return x.u;
}

// ---------------------------------------------------------------- convert ---
// blocks 0..2047: Wq/Wk/Wv/Wo f32->f16 (512 blocks each).
// blocks 2048..2049: per-batch padding length (dual-layout bool detector).
// X (q/k/v) is no longer converted here — the proj GEMM reads f32 directly.
__global__ __launch_bounds__(256) void convert_w(
    const float* __restrict__ wq, const float* __restrict__ wk, const float* __restrict__ wv,
    const float* __restrict__ wo, const void* __restrict__ kpm_raw,
    f16* __restrict__ wh, int* __restrict__ lens_out) {
  int bid = blockIdx.x;
  if (bid >= 2048) {                // padding length for batch b
    int b = bid - 2048;
    __shared__ int s_c8, s_c32;
    if (threadIdx.x == 0) { s_c8 = 0; s_c32 = 0; }
    __syncthreads();
    int tid = threadIdx.x, lane = tid & 63;
    {
      const unsigned char* k8 = (const unsigned char*)kpm_raw + (long)b * T_;
      int cnt = 0;
      for (int j = tid; j < T_; j += 256) cnt += (k8[j] == 0) ? 1 : 0;
#pragma unroll
      for (int off = 1; off < 64; off <<= 1) cnt += __shfl_xor(cnt, off);
      if (lane == 0) atomicAdd(&s_c8, cnt);
    }
    {
      const int* k32 = (const int*)kpm_raw + (long)b * T_;
      int cnt = 0;
      for (int j = tid; j < T_; j += 256) cnt += (k32[j] == 0) ? 1 : 0;
#pragma unroll
      for (int off = 1; off < 64; off <<= 1) cnt += __shfl_xor(cnt, off);
      if (lane == 0) atomicAdd(&s_c32, cnt);
    }
    __syncthreads();
    if (tid == 0) lens_out[b] = (s_c8 == T_) ? s_c32 : s_c8;
    return;
  }
  int r = bid >> 9;
  const float* src = (r == 0) ? wq : (r == 1) ? wk : (r == 2) ? wv : wo;
  f16* dst = wh + (long)r * 1048576;
  long base = (long)(bid & 511) * 2048;
  long e = base + (long)threadIdx.x * 8;
  const float4* s4 = (const float4*)(src + e);
  float4 f0 = s4[0], f1 = s4[1];
  f16x8 o;
  o[0] = (f16)f0.x; o[1] = (f16)f0.y; o[2] = (f16)f0.z; o[3] = (f16)f0.w;
  o[4] = (f16)f1.x; o[5] = (f16)f1.y; o[6] = (f16)f1.z; o[7] = (f16)f1.w;
  *(f16x8*)(dst + e) = o;
}

// ------------------------------------------------------------------- GEMM ---
// C = A(MxK) * W(NxK)^T.  M=4096, N=K=1024.  128x128 tile, BK=32, 8 waves
// (wave = 64x32 output), 2-slot double-buffered LDS (r14 structure).
// __launch_bounds__(512, 6): VGPR cap ~85 (6 waves/SIMD, r14's best point) —
// without it the allocator picked VGPR=36 and sank the f32 A prefetch to its
// use point, exposing full memory latency every K-step (r18 post-mortem).
// AF32=true (proj): A read directly as f32 from q/k/v, converted in-register
//   (RNE casts) and ds_write'd to LDS — kills the separate X convert pass.
// AF32=false (out): A is f16 (Ao), staged via global_load_lds.
// B always f16 via global_load_lds.  2-way-optimal XOR chunk swizzle
// s(r)=((r&3)+((r>>2)&3))&3 on source + reader.  + XCD chunked swizzle.
// modes: 0 -> Qh (f16, *0.125*log2e)  1 -> Kh  2 -> Vt [b,h,dh,t]  3 -> f32
template <bool AF32>
__global__ __launch_bounds__(512, 6) void gemm_k(
    const float* __restrict__ Aq, const float* __restrict__ Ak,
    const float* __restrict__ Av, const f16* __restrict__ A16,
    const f16* __restrict__ Wbase,
    f16* __restrict__ Qb, f16* __restrict__ Kb, f16* __restrict__ Vt,
    float* __restrict__ Co) {
  __shared__ __align__(16) f16 As[2][4096];   // [buf][row*32 + phys_chunk*8]
  __shared__ __align__(16) f16 Bs[2][4096];
  const int K = 1024, N = 1024;

  // XCD-aware chunked swizzle (nwg = 768 or 256, both %8==0 -> bijective)
  int gx = gridDim.x, gy = gridDim.y;
  int nwg = gx * gy * gridDim.z;
  int bid = blockIdx.x + gx * (blockIdx.y + gy * blockIdx.z);
  int cpx = nwg >> 3;
  int wg = (bid & 7) * cpx + (bid >> 3);
  int bz = wg / (gx * gy);
  int rem = wg - bz * gx * gy;
  int by = rem / gx, bx = rem - by * gx;

  int mode = AF32 ? bz : 3;
  const float* A32 = nullptr;
  const f16*   Af  = nullptr;
  if (AF32) A32 = (bz == 0) ? Aq : (bz == 1) ? Ak : Av;
  else      Af  = A16;
  const f16* W = AF32 ? (Wbase + (long)bz * 1048576) : Wbase;

  int m0 = by * 128, n0 = bx * 128;
  int tid = threadIdx.x, lane = tid & 63, w = tid >> 6;
  int wr = w >> 2, wc = w & 3;     // wave tile: rows wr*64, cols wc*32

  // stage: thread covers row srow (0..127), physical 16B chunk sp (0..3);
  // global source column is the XOR-swizzled logical chunk.
  int srow = tid >> 2;
  int sp   = tid & 3;
  int ss   = ((srow & 3) + ((srow >> 2) & 3)) & 3;
  int scol = (sp ^ ss) * 8;        // element units (f16 or f32)
  const float* pa32 = AF32 ? (A32 + (long)(m0 + srow) * K + scol) : nullptr;
  const f16*   pa16 = AF32 ? nullptr : (Af + (long)(m0 + srow) * K + scol);
  const f16*   pb   = W + (long)(n0 + srow) * K + scol;
  int ldst = tid * 8;              // linear LDS dest (f16 units) = tid*16B

  f32x4 acc[4][2] = {};
  int row = lane & 15;
  int rs  = ((row & 3) + ((row >> 2) & 3)) & 3;
  int kq  = ((lane >> 4) ^ rs) * 8;   // swizzled read chunk (f16 units)

  float4 fa0, fa1;                 // in-flight f32 A chunk (AF32 path)
  auto LOADA32 = [&](int k0) {
    const float4* p = (const float4*)(pa32 + k0);
    fa0 = p[0]; fa1 = p[1];
  };
  auto WRITEA = [&](int bsel) {    // RNE casts, 16B ds_write
    f16x8 h;
    h[0] = (f16)fa0.x; h[1] = (f16)fa0.y; h[2] = (f16)fa0.z; h[3] = (f16)fa0.w;
    h[4] = (f16)fa1.x; h[5] = (f16)fa1.y; h[6] = (f16)fa1.z; h[7] = (f16)fa1.w;
    *(f16x8*)&As[bsel][ldst] = h;
  };

  // prologue: tile 0
  if (AF32) {
    LOADA32(0);
    WRITEA(0);                             // compiler waits the f32 loads
    async_ld16(pb, &Bs[0][ldst]);
  } else {
    async_ld16(pa16, &As[0][ldst]);
    async_ld16(pb,   &Bs[0][ldst]);
  }
  asm volatile("s_waitcnt vmcnt(0) lgkmcnt(0)" ::: "memory");
  __builtin_amdgcn_s_barrier();

  int cur = 0;
  for (int k0 = 0; k0 < K; k0 += 32) {
    bool more = (k0 + 32 < K);
    if (more) {
      if (AF32) {
        LOADA32(k0 + 32);                  // issue f32 loads early (ride over compute)
        async_ld16(pb + k0 + 32, &Bs[cur ^ 1][ldst]);
      } else {
        async_ld16(pa16 + k0 + 32, &As[cur ^ 1][ldst]);
        async_ld16(pb   + k0 + 32, &Bs[cur ^ 1][ldst]);
      }
    }
    f16x8 af[4], bfr[2];
#pragma unroll
    for (int m = 0; m < 4; m++)
      af[m] = *(const f16x8*)&As[cur][(wr * 64 + m * 16 + row) * 32 + kq];
#pragma unroll
    for (int n = 0; n < 2; n++)
      bfr[n] = *(const f16x8*)&Bs[cur][(wc * 32 + n * 16 + row) * 32 + kq];
#pragma unroll
    for (int m = 0; m < 4; m++)
#pragma unroll
      for (int n = 0; n < 2; n++)
        acc[m][n] = __builtin_amdgcn_mfma_f32_16x16x32_f16(af[m], bfr[n], acc[m][n], 0, 0, 0);
    if (AF32 && more) WRITEA(cur ^ 1);     // convert + LDS write (late)
    asm volatile("s_waitcnt vmcnt(0) lgkmcnt(0)" ::: "memory");
    __builtin_amdgcn_s_barrier();
    cur ^= 1;
  }

  int r0 = (lane >> 4) * 4;
#pragma unroll
  for (int m = 0; m < 4; m++) {
    int gmb = m0 + wr * 64 + m * 16 + r0;
#pragma unroll
    for (int n = 0; n < 2; n++) {
      int gn = n0 + wc * 32 + n * 16 + row;
      if (mode == 0) {
        // 0.125 (1/sqrt(DH)) * log2(e): attention works in exp2 domain
#pragma unroll
        for (int i = 0; i < 4; i++)
          Qb[(long)(gmb + i) * N + gn] = (f16)(acc[m][n][i] * 0.18033688f);
      } else if (mode == 1) {
#pragma unroll
        for (int i = 0; i < 4; i++)
          Kb[(long)(gmb + i) * N + gn] = (f16)acc[m][n][i];
      } else if (mode == 2) {
        int b = gmb >> 11;
        int t = gmb & 2047;
        int h = gn >> 6, dh = gn & 63;
        f16x4 pk;
#pragma unroll
        for (int i = 0; i < 4; i++) pk[i] = (f16)acc[m][n][i];
        *(f16x4*)&Vt[(long)((b * 16 + h) * 64 + dh) * 2048 + t] = pk;
      } else {
#pragma unroll
        for (int i = 0; i < 4; i++)
          Co[(long)(gmb + i) * N + gn] = acc[m][n][i];
      }
    }
  }
}

// -------------------------------------------------------------- attention ---
// LDS-staged flash attention, exp2-domain softmax, KVBLK=128 per round
// (two 64-key sub-tiles, joint online-softmax update), permlane32_swap for
// the P-fragment half-exchange. Block = 4 waves = 128 q-rows.
// (r14 best config: no setprio, no defer-max — both measured regressions.)
__global__ __launch_bounds__(256, 2) void attn_k(
    const f16* __restrict__ Q, const f16* __restrict__ Kp,
    const f16* __restrict__ Vt, const int* __restrict__ Lens,
    f16* __restrict__ Ao) {
  __shared__ __align__(16) f16 Kl[4][4096];   // 4 x 8KB K 64-tiles
  __shared__ __align__(16) f16 Vl[4][4096];   // 4 x 8KB V^T 64-tiles

  int tid = threadIdx.x, lane = tid & 63, w = tid >> 6;
  int bh = blockIdx.x;
  int j  = blockIdx.y;
  int qm = (j < 8) ? (15 - j) : (j - 8);   // anticorrelated length pairing
  int b = bh >> 4, h = bh & 15;
  int r31 = lane & 31, hi = lane >> 5, hi8 = hi * 8;

  int len = Lens[b];
  int q0 = qm * 128;
  int q0w = q0 + w * 32;
  int gq = q0w + r31;

  int blk_kmax = min(q0 + 128, len);       // block-level visible keys
  int wav_kmax = min(q0w + 32, len);       // this wave's visible keys
  int NR = (blk_kmax + 127) >> 7;          // block-uniform 128-wide rounds

  const f16* Qh = Q  + (long)b * T_ * D_ + h * 64;
  const f16* Kh = Kp + (long)b * T_ * D_ + h * 64;
  const f16* Vh = Vt + (long)(b * 16 + h) * 64 * T_;

  // stage-source constants: thread covers rows srow, srow+8 (shot s), chunk sc
  int srow = w * 16 + (lane >> 3);
  int sc8  = ((lane & 7) ^ ((lane >> 3) & 7)) * 8;   // swizzled 16B-chunk, f16 elems
  int ldst = w * 1024 + lane * 8;                    // f16 elems; +512 for shot 1

  // reader swizzled chunk offsets (constant per lane): logical chunk 2t+hi
  int coff[4];
#pragma unroll
  for (int t = 0; t < 4; t++) coff[t] = ((2 * t + hi) ^ (r31 & 7)) * 8;

  auto STAGE64 = [&](int t, int bsel) {    // tile t (64 keys) -> buffer bsel
    int kb = t * 64;                       // rows always < 2048: in-bounds
#pragma unroll
    for (int s = 0; s < 2; s++) {
      int row = srow + s * 8;
      async_ld16(Kh + (long)(kb + row) * D_ + sc8, &Kl[bsel][ldst + s * 512]);
      async_ld16(Vh + (long)row * T_ + kb + sc8,   &Vl[bsel][ldst + s * 512]);
    }
  };

  // Q fragments: lane holds Q[gq][16t + hi*8 .. +8]
  STAGE64(0, 0);
  STAGE64(1, 1);
  f16x8 qf[4];
#pragma unroll
  for (int t = 0; t < 4; t++)
    qf[t] = *(const f16x8*)(Qh + (long)gq * D_ + t * 16 + hi8);

  f32x16 o0 = {}, o1 = {};       // O^T partials: dh-tiles 0 (0..31), 1 (32..63)
  float mrun = -1e30f, lrun = 0.f;

  auto QK = [&](int buf, f32x16& sa, f32x16& sb) {
#pragma unroll
    for (int tq = 0; tq < 4; tq++) {
      f16x8 k0 = *(const f16x8*)&Kl[buf][(r31)      * 64 + coff[tq]];
      f16x8 k1 = *(const f16x8*)&Kl[buf][(32 + r31) * 64 + coff[tq]];
      sa = __builtin_amdgcn_mfma_f32_32x32x16_f16(k0, qf[tq], sa, 0, 0, 0);
      sb = __builtin_amdgcn_mfma_f32_32x32x16_f16(k1, qf[tq], sb, 0, 0, 0);
    }
  };

  auto MASK = [&](f32x16& sa, f32x16& sb, int kb) {
#pragma unroll
    for (int r = 0; r < 16; r++) {
      int pat = (r & 3) + 8 * (r >> 2) + 4 * hi;
      int gk0 = kb + pat, gk1 = kb + 32 + pat;
      if (gk0 > gq || gk0 >= len) sa[r] = -1e30f;
      if (gk1 > gq || gk1 >= len) sb[r] = -1e30f;
    }
  };

  // pack P (exp2'd scores) -> PV fragments via v_permlane32_swap_b32, 8 MFMA
  auto PV = [&](int bufV, f32x16& sa, f32x16& sb) {
    u32 a0 = pkrtz(sa[0],  sa[1]),  a1 = pkrtz(sa[2],  sa[3]);
    u32 b0 = pkrtz(sa[4],  sa[5]),  b1 = pkrtz(sa[6],  sa[7]);
    u32 c0 = pkrtz(sa[8],  sa[9]),  c1 = pkrtz(sa[10], sa[11]);
    u32 d0 = pkrtz(sa[12], sa[13]), d1 = pkrtz(sa[14], sa[15]);
    u32 e0 = pkrtz(sb[0],  sb[1]),  e1 = pkrtz(sb[2],  sb[3]);
    u32 f0_ = pkrtz(sb[4],  sb[5]), f1_ = pkrtz(sb[6],  sb[7]);
    u32 g0 = pkrtz(sb[8],  sb[9]),  g1 = pkrtz(sb[10], sb[11]);
    u32 h0 = pkrtz(sb[12], sb[13]), h1 = pkrtz(sb[14], sb[15]);
    // swap(X,Y): X <- {X.lo | Y.from-lo-for-hi}, Y <- {X.from-hi-for-lo | Y.hi}
    asm("v_permlane32_swap_b32 %0, %1" : "+v"(a0), "+v"(b0));
    asm("v_permlane32_swap_b32 %0, %1" : "+v"(a1), "+v"(b1));
    asm("v_permlane32_swap_b32 %0, %1" : "+v"(c0), "+v"(d0));
    asm("v_permlane32_swap_b32 %0, %1" : "+v"(c1), "+v"(d1));
    asm("v_permlane32_swap_b32 %0, %1" : "+v"(e0), "+v"(f0_));
    asm("v_permlane32_swap_b32 %0, %1" : "+v"(e1), "+v"(f1_));
    asm("v_permlane32_swap_b32 %0, %1" : "+v"(g0), "+v"(h0));
    asm("v_permlane32_swap_b32 %0, %1" : "+v"(g1), "+v"(h1));
    union { u32 w[4]; f16x8 v; } f00, f01, f10, f11;
    f00.w[0] = a0;  f00.w[1] = a1;  f00.w[2] = b0;  f00.w[3] = b1;
    f01.w[0] = c0;  f01.w[1] = c1;  f01.w[2] = d0;  f01.w[3] = d1;
    f10.w[0] = e0;  f10.w[1] = e1;  f10.w[2] = f0_; f10.w[3] = f1_;
    f11.w[0] = g0;  f11.w[1] = g1;  f11.w[2] = h0;  f11.w[3] = h1;

    f16x8 v00 = *(const f16x8*)&Vl[bufV][(r31)      * 64 + coff[0]];
    f16x8 v01 = *(const f16x8*)&Vl[bufV][(r31)      * 64 + coff[1]];
    f16x8 v02 = *(const f16x8*)&Vl[bufV][(r31)      * 64 + coff[2]];
    f16x8 v03 = *(const f16x8*)&Vl[bufV][(r31)      * 64 + coff[3]];
    f16x8 v10 = *(const f16x8*)&Vl[bufV][(32 + r31) * 64 + coff[0]];
    f16x8 v11 = *(const f16x8*)&Vl[bufV][(32 + r31) * 64 + coff[1]];
    f16x8 v12 = *(const f16x8*)&Vl[bufV][(32 + r31) * 64 + coff[2]];
    f16x8 v13 = *(const f16x8*)&Vl[bufV][(32 + r31) * 64 + coff[3]];

    o0 = __builtin_amdgcn_mfma_f32_32x32x16_f16(v00, f00.v, o0, 0, 0, 0);
    o0 = __builtin_amdgcn_mfma_f32_32x32x16_f16(v01, f01.v, o0, 0, 0, 0);
    o0 = __builtin_amdgcn_mfma_f32_32x32x16_f16(v02, f10.v, o0, 0, 0, 0);
    o0 = __builtin_amdgcn_mfma_f32_32x32x16_f16(v03, f11.v, o0, 0, 0, 0);
    o1 = __builtin_amdgcn_mfma_f32_32x32x16_f16(v10, f00.v, o1, 0, 0, 0);
    o1 = __builtin_amdgcn_mfma_f32_32x32x16_f16(v11, f01.v, o1, 0, 0, 0);
    o1 = __builtin_amdgcn_mfma_f32_32x32x16_f16(v12, f10.v, o1, 0, 0, 0);
    o1 = __builtin_amdgcn_mfma_f32_32x32x16_f16(v13, f11.v, o1, 0, 0, 0);
  };

  asm volatile("s_waitcnt vmcnt(0)" ::: "memory");
  __syncthreads();

  for (int r = 0; r < NR; r++) {
    int t0 = 2 * r;
    int b0buf = t0 & 3, b1buf = (t0 + 1) & 3;
    if (r + 1 < NR) { STAGE64(t0 + 2, (t0 + 2) & 3); STAGE64(t0 + 3, (t0 + 3) & 3); }

    int kb = r * 128;
    if (kb < wav_kmax) {
      bool has2 = (kb + 64) < wav_kmax;
      f32x16 s0 = {}, s1 = {}, s2, s3;
#pragma unroll
      for (int i = 0; i < 16; i++) { s2[i] = -1e30f; s3[i] = -1e30f; }

      QK(b0buf, s0, s1);
      if (has2) {
        f32x16 z0 = {}, z1 = {};
        QK(b1buf, z0, z1);
        s2 = z0; s3 = z1;
      }
      if (kb + 128 > q0w || kb + 128 > len) {
        MASK(s0, s1, kb);
        if (has2) MASK(s2, s3, kb + 64);
      }

      // joint max over (up to) 128 scores: tree + one half-exchange
      float t16[16];
#pragma unroll
      for (int rr = 0; rr < 16; rr++)
        t16[rr] = fmaxf(fmaxf(s0[rr], s1[rr]), fmaxf(s2[rr], s3[rr]));
#pragma unroll
      for (int s = 8; s > 0; s >>= 1)
#pragma unroll
        for (int rr = 0; rr < s; rr++) t16[rr] = fmaxf(t16[rr], t16[rr + s]);
      float mx = fmaxf(t16[0], __shfl_xor(t16[0], 32));

      float mnew = fmaxf(mrun, mx);
      float sf = exp2f(mrun - mnew);    // exp2 domain (log2e folded into Q)
      mrun = mnew;

      float ps[4] = {0.f, 0.f, 0.f, 0.f};
#pragma unroll
      for (int rr = 0; rr < 16; rr++) {
        s0[rr] = exp2f(s0[rr] - mnew);  ps[rr & 3] += s0[rr];
        s1[rr] = exp2f(s1[rr] - mnew);  ps[rr & 3] += s1[rr];
      }
      if (has2) {
#pragma unroll
        for (int rr = 0; rr < 16; rr++) {
          s2[rr] = exp2f(s2[rr] - mnew);  ps[rr & 3] += s2[rr];
          s3[rr] = exp2f(s3[rr] - mnew);  ps[rr & 3] += s3[rr];
        }
      }
      float psum = (ps[0] + ps[1]) + (ps[2] + ps[3]);
      lrun = lrun * sf + psum + __shfl_xor(psum, 32);

      o0 *= sf;
      o1 *= sf;

      PV(b0buf, s0, s1);
      if (has2) PV(b1buf, s2, s3);
    }

    asm volatile("s_waitcnt vmcnt(0)" ::: "memory");
    __syncthreads();
  }

  float linv = 1.f / lrun;
  f16* Aob = Ao + (long)(b * T_ + gq) * D_ + h * 64 + 4 * hi;
#pragma unroll
  for (int g = 0; g < 4; g++) {
    f16x4 s0, s1;
#pragma unroll
    for (int i = 0; i < 4; i++) {
      s0[i] = (f16)(o0[g * 4 + i] * linv);
      s1[i] = (f16)(o1[g * 4 + i] * linv);
    }
    *(f16x4*)(Aob + 8 * g)      = s0;
    *(f16x4*)(Aob + 32 + 8 * g) = s1;
  }
}

// ------------------------------------------------------------------ launch ---
extern "C" void kernel_launch(void* const* d_in, const int* in_sizes, int n_in,
                              void* d_out, int out_size, void* d_ws, size_t ws_size,
                              hipStream_t stream) {
  const float* q  = (const float*)d_in[0];
  const float* k  = (const float*)d_in[1];
  const float* v  = (const float*)d_in[2];
  // d_in[3] = causal mask (analytic, unused)
  const void* kpm = d_in[4];
  const float* wq = (const float*)d_in[5];
  const float* wk = (const float*)d_in[6];
  const float* wv = (const float*)d_in[7];
  const float* wo = (const float*)d_in[8];

  char* ws = (char*)d_ws;
  f16* Wh = (f16*)(ws);                     // 4 * 2 MB
  f16* Qb = (f16*)(ws + 8388608);           // 8 MB
  f16* Kb = (f16*)(ws + 16777216);          // 8 MB
  f16* Vt = (f16*)(ws + 25165824);          // 8 MB
  f16* Ao = (f16*)(ws + 33554432);          // 8 MB  (total 40 MB)
  // Lens scratch: first 2 ints of d_out — read by attn, then fully
  // overwritten by the final GEMM.
  int* Lens = (int*)d_out;

  convert_w<<<2050, 256, 0, stream>>>(wq, wk, wv, wo, kpm, Wh, Lens);

  gemm_k<true><<<dim3(8, 32, 3), 512, 0, stream>>>(
      q, k, v, nullptr, Wh, Qb, Kb, Vt, nullptr);

  attn_k<<<dim3(B_ * H_, T_ / 128), 256, 0, stream>>>(Qb, Kb, Vt, Lens, Ao);

  gemm_k<false><<<dim3(8, 32, 1), 512, 0, stream>>>(
      nullptr, nullptr, nullptr, Ao, Wh + 3 * 1048576, nullptr, nullptr, nullptr,
      (float*)d_out);
}

// Round 23
// 113.408 us; speedup vs baseline: 1.0811x; 1.0066x over previous
//
#include <hip/hip_runtime.h>

#define B_  2
#define T_  2048
#define D_  1024
#define H_  16
#define DH_ 64
#define M_  4096   // B*T

typedef _Float16 f16;
typedef _Float16 f16x8 __attribute__((ext_vector_type(8)));
typedef _Float16 f16x4 __attribute__((ext_vector_type(4)));
typedef __fp16   fp16x2 __attribute__((ext_vector_type(2)));
typedef float    f32x4  __attribute__((ext_vector_type(4)));
typedef float    f32x16 __attribute__((ext_vector_type(16)));
typedef unsigned int u32;

__device__ __forceinline__ void async_ld16(const void* g, void* l) {
  __builtin_amdgcn_global_load_lds(
      (const __attribute__((address_space(1))) unsigned int*)g,
      (__attribute__((address_space(3))) unsigned int*)l,
      16, 0, 0);
}

__device__ __forceinline__ u32 pkrtz(float a, float b) {
  union { fp16x2 h; u32 u; } x;
  x.h = __builtin_amdgcn_cvt_pkrtz(a, b);
  return x.u;
}

// ---------------------------------------------------------------- convert ---
// blocks 0..2047: Wq/Wk/Wv/Wo f32->f16 (512 blocks each).
// blocks 2048..2049: per-batch padding length (dual-layout bool detector).
// X (q/k/v) is not converted here — the proj GEMM reads f32 directly.
__global__ __launch_bounds__(256) void convert_w(
    const float* __restrict__ wq, const float* __restrict__ wk, const float* __restrict__ wv,
    const float* __restrict__ wo, const void* __restrict__ kpm_raw,
    f16* __restrict__ wh, int* __restrict__ lens_out) {
  int bid = blockIdx.x;
  if (bid >= 2048) {                // padding length for batch b
    int b = bid - 2048;
    __shared__ int s_c8, s_c32;
    if (threadIdx.x == 0) { s_c8 = 0; s_c32 = 0; }
    __syncthreads();
    int tid = threadIdx.x, lane = tid & 63;
    {
      const unsigned char* k8 = (const unsigned char*)kpm_raw + (long)b * T_;
      int cnt = 0;
      for (int j = tid; j < T_; j += 256) cnt += (k8[j] == 0) ? 1 : 0;
#pragma unroll
      for (int off = 1; off < 64; off <<= 1) cnt += __shfl_xor(cnt, off);
      if (lane == 0) atomicAdd(&s_c8, cnt);
    }
    {
      const int* k32 = (const int*)kpm_raw + (long)b * T_;
      int cnt = 0;
      for (int j = tid; j < T_; j += 256) cnt += (k32[j] == 0) ? 1 : 0;
#pragma unroll
      for (int off = 1; off < 64; off <<= 1) cnt += __shfl_xor(cnt, off);
      if (lane == 0) atomicAdd(&s_c32, cnt);
    }
    __syncthreads();
    if (tid == 0) lens_out[b] = (s_c8 == T_) ? s_c32 : s_c8;
    return;
  }
  int r = bid >> 9;
  const float* src = (r == 0) ? wq : (r == 1) ? wk : (r == 2) ? wv : wo;
  f16* dst = wh + (long)r * 1048576;
  long base = (long)(bid & 511) * 2048;
  long e = base + (long)threadIdx.x * 8;
  const float4* s4 = (const float4*)(src + e);
  float4 f0 = s4[0], f1 = s4[1];
  f16x8 o;
  o[0] = (f16)f0.x; o[1] = (f16)f0.y; o[2] = (f16)f0.z; o[3] = (f16)f0.w;
  o[4] = (f16)f1.x; o[5] = (f16)f1.y; o[6] = (f16)f1.z; o[7] = (f16)f1.w;
  *(f16x8*)(dst + e) = o;
}

// ------------------------------------------------------------------- GEMM ---
// C = A(MxK) * W(NxK)^T.  M=4096, N=K=1024.  128x128 tile, BK=32, 8 waves
// (wave = 64x32 output), 2-slot double-buffered LDS.
// AF32=true (proj): A read directly as f32 from q/k/v, converted in-register
//   (RNE casts) and ds_write'd to LDS — no separate X convert pass.
// AF32=false (out): A is f16 (Ao), staged via global_load_lds.
// B always f16 via global_load_lds.  2-way-optimal XOR chunk swizzle
// s(r)=((r&3)+((r>>2)&3))&3 on source + reader.  + XCD chunked swizzle.
// modes: 0 -> Qh (f16, *0.125*log2e)  1 -> Kh  2 -> Vt [b,h,dh,t]  3 -> f32
template <bool AF32>
__global__ __launch_bounds__(512, 6) void gemm_k(
    const float* __restrict__ Aq, const float* __restrict__ Ak,
    const float* __restrict__ Av, const f16* __restrict__ A16,
    const f16* __restrict__ Wbase,
    f16* __restrict__ Qb, f16* __restrict__ Kb, f16* __restrict__ Vt,
    float* __restrict__ Co) {
  __shared__ __align__(16) f16 As[2][4096];
  __shared__ __align__(16) f16 Bs[2][4096];
  const int K = 1024, N = 1024;

  int gx = gridDim.x, gy = gridDim.y;
  int nwg = gx * gy * gridDim.z;
  int bid = blockIdx.x + gx * (blockIdx.y + gy * blockIdx.z);
  int cpx = nwg >> 3;
  int wg = (bid & 7) * cpx + (bid >> 3);
  int bz = wg / (gx * gy);
  int rem = wg - bz * gx * gy;
  int by = rem / gx, bx = rem - by * gx;

  int mode = AF32 ? bz : 3;
  const float* A32 = nullptr;
  const f16*   Af  = nullptr;
  if (AF32) A32 = (bz == 0) ? Aq : (bz == 1) ? Ak : Av;
  else      Af  = A16;
  const f16* W = AF32 ? (Wbase + (long)bz * 1048576) : Wbase;

  int m0 = by * 128, n0 = bx * 128;
  int tid = threadIdx.x, lane = tid & 63, w = tid >> 6;
  int wr = w >> 2, wc = w & 3;

  int srow = tid >> 2;
  int sp   = tid & 3;
  int ss   = ((srow & 3) + ((srow >> 2) & 3)) & 3;
  int scol = (sp ^ ss) * 8;
  const float* pa32 = AF32 ? (A32 + (long)(m0 + srow) * K + scol) : nullptr;
  const f16*   pa16 = AF32 ? nullptr : (Af + (long)(m0 + srow) * K + scol);
  const f16*   pb   = W + (long)(n0 + srow) * K + scol;
  int ldst = tid * 8;

  f32x4 acc[4][2] = {};
  int row = lane & 15;
  int rs  = ((row & 3) + ((row >> 2) & 3)) & 3;
  int kq  = ((lane >> 4) ^ rs) * 8;

  float4 fa0, fa1;
  auto LOADA32 = [&](int k0) {
    const float4* p = (const float4*)(pa32 + k0);
    fa0 = p[0]; fa1 = p[1];
  };
  auto WRITEA = [&](int bsel) {
    f16x8 h;
    h[0] = (f16)fa0.x; h[1] = (f16)fa0.y; h[2] = (f16)fa0.z; h[3] = (f16)fa0.w;
    h[4] = (f16)fa1.x; h[5] = (f16)fa1.y; h[6] = (f16)fa1.z; h[7] = (f16)fa1.w;
    *(f16x8*)&As[bsel][ldst] = h;
  };

  if (AF32) {
    LOADA32(0);
    WRITEA(0);
    async_ld16(pb, &Bs[0][ldst]);
  } else {
    async_ld16(pa16, &As[0][ldst]);
    async_ld16(pb,   &Bs[0][ldst]);
  }
  asm volatile("s_waitcnt vmcnt(0) lgkmcnt(0)" ::: "memory");
  __builtin_amdgcn_s_barrier();

  int cur = 0;
  for (int k0 = 0; k0 < K; k0 += 32) {
    bool more = (k0 + 32 < K);
    if (more) {
      if (AF32) {
        LOADA32(k0 + 32);
        async_ld16(pb + k0 + 32, &Bs[cur ^ 1][ldst]);
      } else {
        async_ld16(pa16 + k0 + 32, &As[cur ^ 1][ldst]);
        async_ld16(pb   + k0 + 32, &Bs[cur ^ 1][ldst]);
      }
    }
    f16x8 af[4], bfr[2];
#pragma unroll
    for (int m = 0; m < 4; m++)
      af[m] = *(const f16x8*)&As[cur][(wr * 64 + m * 16 + row) * 32 + kq];
#pragma unroll
    for (int n = 0; n < 2; n++)
      bfr[n] = *(const f16x8*)&Bs[cur][(wc * 32 + n * 16 + row) * 32 + kq];
#pragma unroll
    for (int m = 0; m < 4; m++)
#pragma unroll
      for (int n = 0; n < 2; n++)
        acc[m][n] = __builtin_amdgcn_mfma_f32_16x16x32_f16(af[m], bfr[n], acc[m][n], 0, 0, 0);
    if (AF32 && more) WRITEA(cur ^ 1);
    asm volatile("s_waitcnt vmcnt(0) lgkmcnt(0)" ::: "memory");
    __builtin_amdgcn_s_barrier();
    cur ^= 1;
  }

  int r0 = (lane >> 4) * 4;
#pragma unroll
  for (int m = 0; m < 4; m++) {
    int gmb = m0 + wr * 64 + m * 16 + r0;
#pragma unroll
    for (int n = 0; n < 2; n++) {
      int gn = n0 + wc * 32 + n * 16 + row;
      if (mode == 0) {
        // 0.125 (1/sqrt(DH)) * log2(e): attention works in exp2 domain
#pragma unroll
        for (int i = 0; i < 4; i++)
          Qb[(long)(gmb + i) * N + gn] = (f16)(acc[m][n][i] * 0.18033688f);
      } else if (mode == 1) {
#pragma unroll
        for (int i = 0; i < 4; i++)
          Kb[(long)(gmb + i) * N + gn] = (f16)acc[m][n][i];
      } else if (mode == 2) {
        int b = gmb >> 11;
        int t = gmb & 2047;
        int h = gn >> 6, dh = gn & 63;
        f16x4 pk;
#pragma unroll
        for (int i = 0; i < 4; i++) pk[i] = (f16)acc[m][n][i];
        *(f16x4*)&Vt[(long)((b * 16 + h) * 64 + dh) * 2048 + t] = pk;
      } else {
#pragma unroll
        for (int i = 0; i < 4; i++)
          Co[(long)(gmb + i) * N + gn] = acc[m][n][i];
      }
    }
  }
}

// -------------------------------------------------------------- attention ---
// LDS-staged flash attention, exp2-domain softmax, KVBLK=128 per round
// (two 64-key sub-tiles, joint online-softmax update), permlane32_swap for
// the P-fragment half-exchange. Block = 4 waves = 128 q-rows.
// (r14 best config — seven structural variants measured worse or equal.)
__global__ __launch_bounds__(256, 2) void attn_k(
    const f16* __restrict__ Q, const f16* __restrict__ Kp,
    const f16* __restrict__ Vt, const int* __restrict__ Lens,
    f16* __restrict__ Ao) {
  __shared__ __align__(16) f16 Kl[4][4096];   // 4 x 8KB K 64-tiles
  __shared__ __align__(16) f16 Vl[4][4096];   // 4 x 8KB V^T 64-tiles

  int tid = threadIdx.x, lane = tid & 63, w = tid >> 6;
  int bh = blockIdx.x;
  int j  = blockIdx.y;
  int qm = (j < 8) ? (15 - j) : (j - 8);   // anticorrelated length pairing
  int b = bh >> 4, h = bh & 15;
  int r31 = lane & 31, hi = lane >> 5, hi8 = hi * 8;

  int len = Lens[b];
  int q0 = qm * 128;
  int q0w = q0 + w * 32;
  int gq = q0w + r31;

  int blk_kmax = min(q0 + 128, len);       // block-level visible keys
  int wav_kmax = min(q0w + 32, len);       // this wave's visible keys
  int NR = (blk_kmax + 127) >> 7;          // block-uniform 128-wide rounds

  const f16* Qh = Q  + (long)b * T_ * D_ + h * 64;
  const f16* Kh = Kp + (long)b * T_ * D_ + h * 64;
  const f16* Vh = Vt + (long)(b * 16 + h) * 64 * T_;

  // stage-source constants: thread covers rows srow, srow+8 (shot s), chunk sc
  int srow = w * 16 + (lane >> 3);
  int sc8  = ((lane & 7) ^ ((lane >> 3) & 7)) * 8;   // swizzled 16B-chunk, f16 elems
  int ldst = w * 1024 + lane * 8;                    // f16 elems; +512 for shot 1

  // reader swizzled chunk offsets (constant per lane): logical chunk 2t+hi
  int coff[4];
#pragma unroll
  for (int t = 0; t < 4; t++) coff[t] = ((2 * t + hi) ^ (r31 & 7)) * 8;

  auto STAGE64 = [&](int t, int bsel) {    // tile t (64 keys) -> buffer bsel
    int kb = t * 64;                       // rows always < 2048: in-bounds
#pragma unroll
    for (int s = 0; s < 2; s++) {
      int row = srow + s * 8;
      async_ld16(Kh + (long)(kb + row) * D_ + sc8, &Kl[bsel][ldst + s * 512]);
      async_ld16(Vh + (long)row * T_ + kb + sc8,   &Vl[bsel][ldst + s * 512]);
    }
  };

  // Q fragments: lane holds Q[gq][16t + hi*8 .. +8]
  STAGE64(0, 0);
  STAGE64(1, 1);
  f16x8 qf[4];
#pragma unroll
  for (int t = 0; t < 4; t++)
    qf[t] = *(const f16x8*)(Qh + (long)gq * D_ + t * 16 + hi8);

  f32x16 o0 = {}, o1 = {};       // O^T partials: dh-tiles 0 (0..31), 1 (32..63)
  float mrun = -1e30f, lrun = 0.f;

  auto QK = [&](int buf, f32x16& sa, f32x16& sb) {
#pragma unroll
    for (int tq = 0; tq < 4; tq++) {
      f16x8 k0 = *(const f16x8*)&Kl[buf][(r31)      * 64 + coff[tq]];
      f16x8 k1 = *(const f16x8*)&Kl[buf][(32 + r31) * 64 + coff[tq]];
      sa = __builtin_amdgcn_mfma_f32_32x32x16_f16(k0, qf[tq], sa, 0, 0, 0);
      sb = __builtin_amdgcn_mfma_f32_32x32x16_f16(k1, qf[tq], sb, 0, 0, 0);
    }
  };

  auto MASK = [&](f32x16& sa, f32x16& sb, int kb) {
#pragma unroll
    for (int r = 0; r < 16; r++) {
      int pat = (r & 3) + 8 * (r >> 2) + 4 * hi;
      int gk0 = kb + pat, gk1 = kb + 32 + pat;
      if (gk0 > gq || gk0 >= len) sa[r] = -1e30f;
      if (gk1 > gq || gk1 >= len) sb[r] = -1e30f;
    }
  };

  // pack P (exp2'd scores) -> PV fragments via v_permlane32_swap_b32, 8 MFMA
  auto PV = [&](int bufV, f32x16& sa, f32x16& sb) {
    u32 a0 = pkrtz(sa[0],  sa[1]),  a1 = pkrtz(sa[2],  sa[3]);
    u32 b0 = pkrtz(sa[4],  sa[5]),  b1 = pkrtz(sa[6],  sa[7]);
    u32 c0 = pkrtz(sa[8],  sa[9]),  c1 = pkrtz(sa[10], sa[11]);
    u32 d0 = pkrtz(sa[12], sa[13]), d1 = pkrtz(sa[14], sa[15]);
    u32 e0 = pkrtz(sb[0],  sb[1]),  e1 = pkrtz(sb[2],  sb[3]);
    u32 f0_ = pkrtz(sb[4],  sb[5]), f1_ = pkrtz(sb[6],  sb[7]);
    u32 g0 = pkrtz(sb[8],  sb[9]),  g1 = pkrtz(sb[10], sb[11]);
    u32 h0 = pkrtz(sb[12], sb[13]), h1 = pkrtz(sb[14], sb[15]);
    // swap(X,Y): X <- {X.lo | Y.from-lo-for-hi}, Y <- {X.from-hi-for-lo | Y.hi}
    asm("v_permlane32_swap_b32 %0, %1" : "+v"(a0), "+v"(b0));
    asm("v_permlane32_swap_b32 %0, %1" : "+v"(a1), "+v"(b1));
    asm("v_permlane32_swap_b32 %0, %1" : "+v"(c0), "+v"(d0));
    asm("v_permlane32_swap_b32 %0, %1" : "+v"(c1), "+v"(d1));
    asm("v_permlane32_swap_b32 %0, %1" : "+v"(e0), "+v"(f0_));
    asm("v_permlane32_swap_b32 %0, %1" : "+v"(e1), "+v"(f1_));
    asm("v_permlane32_swap_b32 %0, %1" : "+v"(g0), "+v"(h0));
    asm("v_permlane32_swap_b32 %0, %1" : "+v"(g1), "+v"(h1));
    union { u32 w[4]; f16x8 v; } f00, f01, f10, f11;
    f00.w[0] = a0;  f00.w[1] = a1;  f00.w[2] = b0;  f00.w[3] = b1;
    f01.w[0] = c0;  f01.w[1] = c1;  f01.w[2] = d0;  f01.w[3] = d1;
    f10.w[0] = e0;  f10.w[1] = e1;  f10.w[2] = f0_; f10.w[3] = f1_;
    f11.w[0] = g0;  f11.w[1] = g1;  f11.w[2] = h0;  f11.w[3] = h1;

    f16x8 v00 = *(const f16x8*)&Vl[bufV][(r31)      * 64 + coff[0]];
    f16x8 v01 = *(const f16x8*)&Vl[bufV][(r31)      * 64 + coff[1]];
    f16x8 v02 = *(const f16x8*)&Vl[bufV][(r31)      * 64 + coff[2]];
    f16x8 v03 = *(const f16x8*)&Vl[bufV][(r31)      * 64 + coff[3]];
    f16x8 v10 = *(const f16x8*)&Vl[bufV][(32 + r31) * 64 + coff[0]];
    f16x8 v11 = *(const f16x8*)&Vl[bufV][(32 + r31) * 64 + coff[1]];
    f16x8 v12 = *(const f16x8*)&Vl[bufV][(32 + r31) * 64 + coff[2]];
    f16x8 v13 = *(const f16x8*)&Vl[bufV][(32 + r31) * 64 + coff[3]];

    o0 = __builtin_amdgcn_mfma_f32_32x32x16_f16(v00, f00.v, o0, 0, 0, 0);
    o0 = __builtin_amdgcn_mfma_f32_32x32x16_f16(v01, f01.v, o0, 0, 0, 0);
    o0 = __builtin_amdgcn_mfma_f32_32x32x16_f16(v02, f10.v, o0, 0, 0, 0);
    o0 = __builtin_amdgcn_mfma_f32_32x32x16_f16(v03, f11.v, o0, 0, 0, 0);
    o1 = __builtin_amdgcn_mfma_f32_32x32x16_f16(v10, f00.v, o1, 0, 0, 0);
    o1 = __builtin_amdgcn_mfma_f32_32x32x16_f16(v11, f01.v, o1, 0, 0, 0);
    o1 = __builtin_amdgcn_mfma_f32_32x32x16_f16(v12, f10.v, o1, 0, 0, 0);
    o1 = __builtin_amdgcn_mfma_f32_32x32x16_f16(v13, f11.v, o1, 0, 0, 0);
  };

  asm volatile("s_waitcnt vmcnt(0)" ::: "memory");
  __syncthreads();

  for (int r = 0; r < NR; r++) {
    int t0 = 2 * r;
    int b0buf = t0 & 3, b1buf = (t0 + 1) & 3;
    if (r + 1 < NR) { STAGE64(t0 + 2, (t0 + 2) & 3); STAGE64(t0 + 3, (t0 + 3) & 3); }

    int kb = r * 128;
    if (kb < wav_kmax) {
      bool has2 = (kb + 64) < wav_kmax;
      f32x16 s0 = {}, s1 = {}, s2, s3;
#pragma unroll
      for (int i = 0; i < 16; i++) { s2[i] = -1e30f; s3[i] = -1e30f; }

      QK(b0buf, s0, s1);
      if (has2) {
        f32x16 z0 = {}, z1 = {};
        QK(b1buf, z0, z1);
        s2 = z0; s3 = z1;
      }
      if (kb + 128 > q0w || kb + 128 > len) {
        MASK(s0, s1, kb);
        if (has2) MASK(s2, s3, kb + 64);
      }

      // joint max over (up to) 128 scores: tree + one half-exchange
      float t16[16];
#pragma unroll
      for (int rr = 0; rr < 16; rr++)
        t16[rr] = fmaxf(fmaxf(s0[rr], s1[rr]), fmaxf(s2[rr], s3[rr]));
#pragma unroll
      for (int s = 8; s > 0; s >>= 1)
#pragma unroll
        for (int rr = 0; rr < s; rr++) t16[rr] = fmaxf(t16[rr], t16[rr + s]);
      float mx = fmaxf(t16[0], __shfl_xor(t16[0], 32));

      float mnew = fmaxf(mrun, mx);
      float sf = exp2f(mrun - mnew);    // exp2 domain (log2e folded into Q)
      mrun = mnew;

      float ps[4] = {0.f, 0.f, 0.f, 0.f};
#pragma unroll
      for (int rr = 0; rr < 16; rr++) {
        s0[rr] = exp2f(s0[rr] - mnew);  ps[rr & 3] += s0[rr];
        s1[rr] = exp2f(s1[rr] - mnew);  ps[rr & 3] += s1[rr];
      }
      if (has2) {
#pragma unroll
        for (int rr = 0; rr < 16; rr++) {
          s2[rr] = exp2f(s2[rr] - mnew);  ps[rr & 3] += s2[rr];
          s3[rr] = exp2f(s3[rr] - mnew);  ps[rr & 3] += s3[rr];
        }
      }
      float psum = (ps[0] + ps[1]) + (ps[2] + ps[3]);
      lrun = lrun * sf + psum + __shfl_xor(psum, 32);

      o0 *= sf;
      o1 *= sf;

      PV(b0buf, s0, s1);
      if (has2) PV(b1buf, s2, s3);
    }

    asm volatile("s_waitcnt vmcnt(0)" ::: "memory");
    __syncthreads();
  }

  float linv = 1.f / lrun;
  f16* Aob = Ao + (long)(b * T_ + gq) * D_ + h * 64 + 4 * hi;
#pragma unroll
  for (int g = 0; g < 4; g++) {
    f16x4 s0, s1;
#pragma unroll
    for (int i = 0; i < 4; i++) {
      s0[i] = (f16)(o0[g * 4 + i] * linv);
      s1[i] = (f16)(o1[g * 4 + i] * linv);
    }
    *(f16x4*)(Aob + 8 * g)      = s0;
    *(f16x4*)(Aob + 32 + 8 * g) = s1;
  }
}

// ------------------------------------------------------------------ launch ---
extern "C" void kernel_launch(void* const* d_in, const int* in_sizes, int n_in,
                              void* d_out, int out_size, void* d_ws, size_t ws_size,
                              hipStream_t stream) {
  const float* q  = (const float*)d_in[0];
  const float* k  = (const float*)d_in[1];
  const float* v  = (const float*)d_in[2];
  // d_in[3] = causal mask (analytic, unused)
  const void* kpm = d_in[4];
  const float* wq = (const float*)d_in[5];
  const float* wk = (const float*)d_in[6];
  const float* wv = (const float*)d_in[7];
  const float* wo = (const float*)d_in[8];

  char* ws = (char*)d_ws;
  f16* Wh = (f16*)(ws);                     // 4 * 2 MB
  f16* Qb = (f16*)(ws + 8388608);           // 8 MB
  f16* Kb = (f16*)(ws + 16777216);          // 8 MB
  f16* Vt = (f16*)(ws + 25165824);          // 8 MB
  f16* Ao = (f16*)(ws + 33554432);          // 8 MB  (total 40 MB)
  // Lens scratch: first 2 ints of d_out — read by attn, then fully
  // overwritten by the final GEMM.
  int* Lens = (int*)d_out;

  convert_w<<<2050, 256, 0, stream>>>(wq, wk, wv, wo, kpm, Wh, Lens);

  gemm_k<true><<<dim3(8, 32, 3), 512, 0, stream>>>(
      q, k, v, nullptr, Wh, Qb, Kb, Vt, nullptr);

  attn_k<<<dim3(B_ * H_, T_ / 128), 256, 0, stream>>>(Qb, Kb, Vt, Lens, Ao);

  gemm_k<false><<<dim3(8, 32, 1), 512, 0, stream>>>(
      nullptr, nullptr, nullptr, Ao, Wh + 3 * 1048576, nullptr, nullptr, nullptr,
      (float*)d_out);
}